// Round 3
// baseline (227.999 us; speedup 1.0000x reference)
//
#include <hip/hip_runtime.h>

// ---------------- types / helpers ----------------
using bf16x8 = __attribute__((ext_vector_type(8))) short;
using f32x4  = __attribute__((ext_vector_type(4))) float;

static __device__ inline unsigned short f2bf(float f) {
  unsigned int u = __float_as_uint(f);
  u += 0x7fffu + ((u >> 16) & 1u);          // round-to-nearest-even
  return (unsigned short)(u >> 16);
}
static __device__ inline unsigned int pk2(float a, float b) {
  return (unsigned int)f2bf(a) | ((unsigned int)f2bf(b) << 16);
}

// butterfly reductions across the 16-lane DPP row (row_ror 1,2,4,8)
#define ROW16_MAX(x) { \
  { int _t = __builtin_amdgcn_update_dpp(0, __float_as_int(x), 0x121, 0xf, 0xf, true); x = fmaxf(x, __int_as_float(_t)); } \
  { int _t = __builtin_amdgcn_update_dpp(0, __float_as_int(x), 0x122, 0xf, 0xf, true); x = fmaxf(x, __int_as_float(_t)); } \
  { int _t = __builtin_amdgcn_update_dpp(0, __float_as_int(x), 0x124, 0xf, 0xf, true); x = fmaxf(x, __int_as_float(_t)); } \
  { int _t = __builtin_amdgcn_update_dpp(0, __float_as_int(x), 0x128, 0xf, 0xf, true); x = fmaxf(x, __int_as_float(_t)); } }
#define ROW16_SUM(x) { \
  { int _t = __builtin_amdgcn_update_dpp(0, __float_as_int(x), 0x121, 0xf, 0xf, true); x += __int_as_float(_t); } \
  { int _t = __builtin_amdgcn_update_dpp(0, __float_as_int(x), 0x122, 0xf, 0xf, true); x += __int_as_float(_t); } \
  { int _t = __builtin_amdgcn_update_dpp(0, __float_as_int(x), 0x124, 0xf, 0xf, true); x += __int_as_float(_t); } \
  { int _t = __builtin_amdgcn_update_dpp(0, __float_as_int(x), 0x128, 0xf, 0xf, true); x += __int_as_float(_t); } }

// ---------------- kernel 0: weight prep (transpose -> bf16) ----------------
__global__ __launch_bounds__(256) void prep_kernel(
    const float* __restrict__ Wq, const float* __restrict__ Wk, const float* __restrict__ Wv,
    const float* __restrict__ Wo, const float* __restrict__ bq, const float* __restrict__ bk,
    const float* __restrict__ bv,
    unsigned short* __restrict__ Wt, unsigned short* __restrict__ Wot, float* __restrict__ bqkv)
{
  int idx = blockIdx.x * 256 + threadIdx.x;
  if (idx < 192 * 1024) {
    int n = idx >> 10, k = idx & 1023;
    const float* W = (n < 64) ? Wq : (n < 128) ? Wk : Wv;
    Wt[idx] = f2bf(W[k * 64 + (n & 63)]);
  } else if (idx < 192 * 1024 + 1024 * 64) {
    int j = idx - 192 * 1024;
    int n = j >> 6, k = j & 63;
    Wot[j] = f2bf(Wo[k * 1024 + n]);
  } else if (idx < 192 * 1024 + 1024 * 64 + 192) {
    int n = idx - (192 * 1024 + 1024 * 64);
    bqkv[n] = (n < 64) ? bq[n] : (n < 128) ? bk[n - 64] : bv[n - 128];
  }
}

// ---------------- kernel 1: QKV projection (bf16 MFMA), X read ONCE ----------------
// X [16384][1024] fp32, Wt [192][1024] bf16 -> qkvb [16384][192] bf16
// BM=32, FULL N=192 per block, BK=64; grid 512 -> 2 blocks/CU, 8 waves/CU.
// Distance-2 register prefetch (E/O reg sets), ping-pong LDS, 1 barrier/K-step.
#define QKV_LOAD(KS, A0, A1, B) { \
  const float* sA_ = srcA + (KS) * 64; \
  A0 = *(const float4*)(sA_); A1 = *(const float4*)(sA_ + 4); \
  const unsigned short* sB_ = srcB + (KS) * 64; \
  _Pragma("unroll") \
  for (int r_ = 0; r_ < 6; ++r_) B[r_] = *(const uint4*)(sB_ + (size_t)r_ * 32 * 1024); }

#define QKV_STORE(BUF, A0, A1, B) { \
  uint4 pv_; \
  pv_.x = pk2(A0.x, A0.y); pv_.y = pk2(A0.z, A0.w); \
  pv_.z = pk2(A1.x, A1.y); pv_.w = pk2(A1.z, A1.w); \
  *(uint4*)(As[BUF] + rowA * 72 + cA * 8) = pv_; \
  _Pragma("unroll") \
  for (int r_ = 0; r_ < 6; ++r_) \
    *(uint4*)(Bs[BUF] + (rowA + 32 * r_) * 72 + cA * 8) = B[r_]; }

#define QKV_MMA(BUF) { \
  _Pragma("unroll") \
  for (int kk = 0; kk < 64; kk += 32) { \
    int ko = kk + quad * 8; \
    bf16x8 afr = *(const bf16x8*)(As[BUF] + (mg * 16 + col) * 72 + ko); \
    _Pragma("unroll") \
    for (int ns = 0; ns < 6; ++ns) { \
      bf16x8 bfr = *(const bf16x8*)(Bs[BUF] + ((ng * 6 + ns) * 16 + col) * 72 + ko); \
      acc[ns] = __builtin_amdgcn_mfma_f32_16x16x32_bf16(afr, bfr, acc[ns], 0, 0, 0); \
    } } }

__global__ __launch_bounds__(256) void qkv_gemm(
    const float* __restrict__ X, const unsigned short* __restrict__ Wt,
    const float* __restrict__ bqkv, unsigned short* __restrict__ qkvb)
{
  __shared__ __align__(16) unsigned short As[2][32 * 72];
  __shared__ __align__(16) unsigned short Bs[2][192 * 72];
  int t = threadIdx.x;
  int lane = t & 63, w = t >> 6;
  int m0 = blockIdx.x * 32;
  int mg = w & 1, ng = w >> 1;               // wave: 16 rows x 96 cols
  int col = lane & 15, quad = lane >> 4;
  f32x4 acc[6] = {};

  int rowA = t >> 3, cA = t & 7;             // A: 32 rows x 8 chunks of 8
  const float* srcA = X + (size_t)(m0 + rowA) * 1024 + cA * 8;
  const unsigned short* srcB = Wt + (size_t)rowA * 1024 + cA * 8;

  float4 eA0, eA1; uint4 eB[6];              // even tiles
  float4 oA0, oA1; uint4 oB[6];              // odd tiles
  QKV_LOAD(0, eA0, eA1, eB);
  QKV_LOAD(1, oA0, oA1, oB);

  for (int ks = 0; ks < 16; ks += 2) {
    QKV_STORE(0, eA0, eA1, eB);
    if (ks + 2 < 16) QKV_LOAD(ks + 2, eA0, eA1, eB);
    __syncthreads();
    QKV_MMA(0);
    // race-free: prev iter's MMA(1) (reads Bs[1]) is separated from this
    // STORE(1) by the barrier above.
    QKV_STORE(1, oA0, oA1, oB);
    if (ks + 3 < 16) QKV_LOAD(ks + 3, oA0, oA1, oB);
    __syncthreads();
    QKV_MMA(1);
  }
  #pragma unroll
  for (int ns = 0; ns < 6; ++ns)
    #pragma unroll
    for (int r = 0; r < 4; ++r) {
      int m = m0 + mg * 16 + quad * 4 + r;
      int n = ng * 96 + ns * 16 + col;
      qkvb[(size_t)m * 192 + n] = f2bf(acc[ns][r] + bqkv[n]);
    }
}

// ---------------- kernel 2: banded flash attention + output projection ----------------
// 512 threads; wave-pairs (p = w>>1) own 16 q-rows; s = w&1 splits the
// 9 j-tiles (5+4) and 5 PV k-chunks (3+2). Cross-wave max/sum/O via LDS.
// Then the normalized O tile (64x64 bf16, LDS) is projected through Wot
// (waves split the 1024 n-cols, 128 each) and written straight to out.
__global__ __launch_bounds__(512) void attn_out(
    const unsigned short* __restrict__ qkvb, const float* __restrict__ bias,
    const unsigned short* __restrict__ Wot, const float* __restrict__ bo,
    float* __restrict__ out)
{
  __shared__ __align__(16) unsigned short Kl[192 * 72];
  __shared__ __align__(16) unsigned short Vt[64 * 216];
  __shared__ __align__(16) unsigned short Ps[4 * 16 * 168];
  __shared__ __align__(16) unsigned short Obf[64 * 72];
  __shared__ float Osum[4][16][64];
  __shared__ float Mx[8][16];
  __shared__ float Lx[8][16];
  __shared__ float biasL[129];

  int t = threadIdx.x;
  int lane = t & 63, w = t >> 6;
  int p = w >> 1, s = w & 1;
  int col = lane & 15, quad = lane >> 4, q4 = quad * 4;
  int bidx = blockIdx.x;
  int b = bidx >> 5;                 // batch
  int i0 = (bidx & 31) * 64;         // first q row (batch coords)
  int jw = i0 - 64;                  // window start (may be <0)
  const unsigned short* qbase = qkvb + (size_t)(b << 11) * 192;

  // Q fragments: issue global loads FIRST so they overlap the staging loop
  int iq = i0 + p * 16;                    // pair's first q row (batch coords)
  const unsigned short* qr = qbase + (size_t)(iq + col) * 192 + quad * 8;
  bf16x8 aq0 = *(const bf16x8*)(qr);
  bf16x8 aq1 = *(const bf16x8*)(qr + 32);

  if (t < 129) biasL[t] = bias[1984 + t];
  // stage window: 192 rows x (64 K + 64 V) bf16 = 16 chunks of 16B per row
  #pragma unroll
  for (int it = 0; it < 6; ++it) {
    int idx = it * 512 + t;
    int row = idx >> 4;                    // 0..191 window row
    int c = idx & 15;                      // 16B chunk within k|v
    int jb = jw + row;
    int jc = jb < 0 ? 0 : (jb > 2047 ? 2047 : jb);
    const unsigned short* src = qbase + (size_t)jc * 192 + 64 + c * 8;
    uint4 v = *(const uint4*)src;
    if (c < 8) {                           // K: direct copy
      *(uint4*)(Kl + row * 72 + c * 8) = v;
    } else {                               // V: transpose store
      union { uint4 u; unsigned short ss[8]; } uv; uv.u = v;
      int p0 = (c - 8) * 8;
      #pragma unroll
      for (int e = 0; e < 8; ++e) Vt[(p0 + e) * 216 + row] = uv.ss[e];
    }
  }
  if (t < 256) { // zero-fill Vt j-cols 192..207 (PV k-chunk overhang)
    int pz = t >> 2, c0 = 192 + (t & 3) * 4;
    *(uint2*)(Vt + pz * 216 + c0) = make_uint2(0u, 0u);
  }
  __syncthreads();

  // QK^T: wave's j-tile subset (s=0: t9 0..4, s=1: t9 5..8)
  int nt9 = 5 - s, t9b = 5 * s;
  f32x4 sv[5];
  for (int i = 0; i < nt9; ++i) {
    int t9 = t9b + i;
    int krow = ((p + t9) * 16 + col) * 72;
    bf16x8 kb0 = *(const bf16x8*)(Kl + krow + quad * 8);
    bf16x8 kb1 = *(const bf16x8*)(Kl + krow + 32 + quad * 8);
    f32x4 z = {};
    z = __builtin_amdgcn_mfma_f32_16x16x32_bf16(aq0, kb0, z, 0, 0, 0);
    sv[i] = __builtin_amdgcn_mfma_f32_16x16x32_bf16(aq1, kb1, z, 0, 0, 0);
  }
  // mask + bias; partial row max
  float mrow[4] = {-3e38f, -3e38f, -3e38f, -3e38f};
  for (int i = 0; i < nt9; ++i) {
    int t9 = t9b + i;
    int j = iq - 64 + t9 * 16 + col;       // batch coords
    #pragma unroll
    for (int r = 0; r < 4; ++r) {
      int diff = q4 + r + 64 - t9 * 16 - col;   // i - j
      bool valid = (j >= 0) & (j < 2048) & (diff >= -64) & (diff <= 64);
      int bi = 64 - diff; bi = bi < 0 ? 0 : (bi > 128 ? 128 : bi);
      float x = valid ? (sv[i][r] * 0.125f + biasL[bi]) : -3e38f;
      sv[i][r] = x;
      mrow[r] = fmaxf(mrow[r], x);
    }
  }
  #pragma unroll
  for (int r = 0; r < 4; ++r) ROW16_MAX(mrow[r]);
  if (col == 0) {
    #pragma unroll
    for (int r = 0; r < 4; ++r) Mx[w][q4 + r] = mrow[r];
  }
  __syncthreads();
  #pragma unroll
  for (int r = 0; r < 4; ++r) mrow[r] = fmaxf(mrow[r], Mx[w ^ 1][q4 + r]);

  unsigned short* Pw = Ps + p * (16 * 168);
  float lsum[4] = {0.f, 0.f, 0.f, 0.f};
  for (int i = 0; i < nt9; ++i) {
    int t9 = t9b + i;
    #pragma unroll
    for (int r = 0; r < 4; ++r) {
      float pe = __expf(sv[i][r] - mrow[r]);
      lsum[r] += pe;
      Pw[(q4 + r) * 168 + t9 * 16 + col] = f2bf(pe);
    }
  }
  #pragma unroll
  for (int r = 0; r < 4; ++r) ROW16_SUM(lsum[r]);
  if (col == 0) {
    #pragma unroll
    for (int r = 0; r < 4; ++r) Lx[w][q4 + r] = lsum[r];
  }
  if (s == 0) {
    #pragma unroll
    for (int r = 0; r < 4; ++r) Pw[(q4 + r) * 168 + 144 + col] = 0;
  }
  __syncthreads();
  #pragma unroll
  for (int r = 0; r < 4; ++r) lsum[r] += Lx[w ^ 1][q4 + r];

  // PV: wave's k-chunk subset (s=0: kc 0..2, s=1: kc 3..4)
  f32x4 o[4] = {};
  int nkc = 3 - s, kcb = 3 * s;
  for (int i = 0; i < nkc; ++i) {
    int kc = kcb + i;
    bf16x8 pa = *(const bf16x8*)(Pw + col * 168 + kc * 32 + quad * 8);
    #pragma unroll
    for (int nt = 0; nt < 4; ++nt) {
      bf16x8 vb = *(const bf16x8*)(Vt + (nt * 16 + col) * 216 + 16 * p + kc * 32 + quad * 8);
      o[nt] = __builtin_amdgcn_mfma_f32_16x16x32_bf16(pa, vb, o[nt], 0, 0, 0);
    }
  }
  if (s == 1) {
    #pragma unroll
    for (int nt = 0; nt < 4; ++nt)
      #pragma unroll
      for (int r = 0; r < 4; ++r)
        Osum[p][q4 + r][nt * 16 + col] = o[nt][r];
  }
  __syncthreads();
  if (s == 0) { // combine halves, normalize, park O tile in LDS as bf16
    float rl[4];
    #pragma unroll
    for (int r = 0; r < 4; ++r) rl[r] = 1.0f / lsum[r];
    #pragma unroll
    for (int nt = 0; nt < 4; ++nt)
      #pragma unroll
      for (int r = 0; r < 4; ++r)
        Obf[(p * 16 + q4 + r) * 72 + nt * 16 + col] =
            f2bf((o[nt][r] + Osum[p][q4 + r][nt * 16 + col]) * rl[r]);
  }
  __syncthreads();

  // ---- output projection: out[64 q][1024 n] = Obf @ Wot + bo ----
  // wave w owns n-cols [w*128, w*128+128); whole Wot slice held in 64 VGPRs.
  const unsigned short* wb_base = Wot + (size_t)(w * 128 + col) * 64 + quad * 8;
  bf16x8 wb[8][2];
  #pragma unroll
  for (int ns = 0; ns < 8; ++ns) {
    wb[ns][0] = *(const bf16x8*)(wb_base + ns * 16 * 64);
    wb[ns][1] = *(const bf16x8*)(wb_base + ns * 16 * 64 + 32);
  }
  float bov[8];
  #pragma unroll
  for (int ns = 0; ns < 8; ++ns) bov[ns] = bo[w * 128 + ns * 16 + col];
  float* outbase = out + ((size_t)(b << 11) + i0) * 1024 + w * 128;
  #pragma unroll
  for (int mt = 0; mt < 4; ++mt) {
    bf16x8 a0 = *(const bf16x8*)(Obf + (mt * 16 + col) * 72 + quad * 8);
    bf16x8 a1 = *(const bf16x8*)(Obf + (mt * 16 + col) * 72 + 32 + quad * 8);
    f32x4 acc8[8] = {};
    #pragma unroll
    for (int ns = 0; ns < 8; ++ns) {
      acc8[ns] = __builtin_amdgcn_mfma_f32_16x16x32_bf16(a0, wb[ns][0], acc8[ns], 0, 0, 0);
      acc8[ns] = __builtin_amdgcn_mfma_f32_16x16x32_bf16(a1, wb[ns][1], acc8[ns], 0, 0, 0);
    }
    #pragma unroll
    for (int ns = 0; ns < 8; ++ns)
      #pragma unroll
      for (int r = 0; r < 4; ++r)
        outbase[(size_t)(mt * 16 + q4 + r) * 1024 + ns * 16 + col] = acc8[ns][r] + bov[ns];
  }
}

// ---------------- launch ----------------
extern "C" void kernel_launch(void* const* d_in, const int* in_sizes, int n_in,
                              void* d_out, int out_size, void* d_ws, size_t ws_size,
                              hipStream_t stream) {
  const float* X    = (const float*)d_in[0];
  // d_in[1] = attention_mask: per-row constant shift -> softmax-invariant, unused
  const float* Wq   = (const float*)d_in[2];
  const float* bq   = (const float*)d_in[3];
  const float* Wk   = (const float*)d_in[4];
  const float* bk   = (const float*)d_in[5];
  const float* Wv   = (const float*)d_in[6];
  const float* bv   = (const float*)d_in[7];
  const float* Wo   = (const float*)d_in[8];
  const float* bo   = (const float*)d_in[9];
  const float* bias = (const float*)d_in[10];
  float* out = (float*)d_out;
  char* ws = (char*)d_ws;
  unsigned short* qkvb = (unsigned short*)(ws);              // 6,291,456 B
  unsigned short* Wt   = (unsigned short*)(ws + 6291456);    //   393,216 B
  unsigned short* Wot  = (unsigned short*)(ws + 6684672);    //   131,072 B
  float*          bqkv = (float*)(ws + 6815744);             //       768 B

  prep_kernel<<<1025, 256, 0, stream>>>(Wq, Wk, Wv, Wo, bq, bk, bv, Wt, Wot, bqkv);
  qkv_gemm<<<512, 256, 0, stream>>>(X, Wt, bqkv, qkvb);
  attn_out<<<256, 512, 0, stream>>>(qkvb, bias, Wot, bo, out);
}

// Round 4
// 175.225 us; speedup vs baseline: 1.3012x; 1.3012x over previous
//
#include <hip/hip_runtime.h>

// ---------------- types / helpers ----------------
using bf16x8 = __attribute__((ext_vector_type(8))) short;
using f32x4  = __attribute__((ext_vector_type(4))) float;

static __device__ inline unsigned short f2bf(float f) {
  unsigned int u = __float_as_uint(f);
  u += 0x7fffu + ((u >> 16) & 1u);          // round-to-nearest-even
  return (unsigned short)(u >> 16);
}
static __device__ inline unsigned int pk2(float a, float b) {
  return (unsigned int)f2bf(a) | ((unsigned int)f2bf(b) << 16);
}

// butterfly reductions across the 16-lane DPP row (row_ror 1,2,4,8)
#define ROW16_MAX(x) { \
  { int _t = __builtin_amdgcn_update_dpp(0, __float_as_int(x), 0x121, 0xf, 0xf, true); x = fmaxf(x, __int_as_float(_t)); } \
  { int _t = __builtin_amdgcn_update_dpp(0, __float_as_int(x), 0x122, 0xf, 0xf, true); x = fmaxf(x, __int_as_float(_t)); } \
  { int _t = __builtin_amdgcn_update_dpp(0, __float_as_int(x), 0x124, 0xf, 0xf, true); x = fmaxf(x, __int_as_float(_t)); } \
  { int _t = __builtin_amdgcn_update_dpp(0, __float_as_int(x), 0x128, 0xf, 0xf, true); x = fmaxf(x, __int_as_float(_t)); } }
#define ROW16_SUM(x) { \
  { int _t = __builtin_amdgcn_update_dpp(0, __float_as_int(x), 0x121, 0xf, 0xf, true); x += __int_as_float(_t); } \
  { int _t = __builtin_amdgcn_update_dpp(0, __float_as_int(x), 0x122, 0xf, 0xf, true); x += __int_as_float(_t); } \
  { int _t = __builtin_amdgcn_update_dpp(0, __float_as_int(x), 0x124, 0xf, 0xf, true); x += __int_as_float(_t); } \
  { int _t = __builtin_amdgcn_update_dpp(0, __float_as_int(x), 0x128, 0xf, 0xf, true); x += __int_as_float(_t); } }

// ---------------- kernel 0: weight prep (transpose -> bf16) ----------------
__global__ __launch_bounds__(256) void prep_kernel(
    const float* __restrict__ Wq, const float* __restrict__ Wk, const float* __restrict__ Wv,
    const float* __restrict__ Wo, const float* __restrict__ bq, const float* __restrict__ bk,
    const float* __restrict__ bv,
    unsigned short* __restrict__ Wt, unsigned short* __restrict__ Wot, float* __restrict__ bqkv)
{
  int idx = blockIdx.x * 256 + threadIdx.x;
  if (idx < 192 * 1024) {
    int n = idx >> 10, k = idx & 1023;
    const float* W = (n < 64) ? Wq : (n < 128) ? Wk : Wv;
    Wt[idx] = f2bf(W[k * 64 + (n & 63)]);
  } else if (idx < 192 * 1024 + 1024 * 64) {
    int j = idx - 192 * 1024;
    int n = j >> 6, k = j & 63;
    Wot[j] = f2bf(Wo[k * 1024 + n]);
  } else if (idx < 192 * 1024 + 1024 * 64 + 192) {
    int n = idx - (192 * 1024 + 1024 * 64);
    bqkv[n] = (n < 64) ? bq[n] : (n < 128) ? bk[n - 64] : bv[n - 128];
  }
}

// ---------------- fused kernel: QKV proj + banded attention + out proj ----------------
// Block = 64 q-rows (grid 256 = 8 batches x 32 tiles), 512 threads = 8 waves.
// Phase 1: window GEMM  [192 window rows] x [192 qkv cols] x K=1024 from X, Wt.
//          (K/V recomputed for 64-row halos; X is L3-resident so re-reads are cheap.)
// Phase 2: banded attention (verified R2 structure; Q/K/V from LDS).
// Phase 3: output projection (verified R3 structure) -> out.
union __align__(16) SharedU {
  struct { unsigned short A[2][192 * 72]; unsigned short B[2][192 * 72]; } p1;
  struct {
    unsigned short Qs[64 * 72];
    unsigned short Kl[192 * 72];
    unsigned short Vt[64 * 216];
    unsigned short Ps[4 * 16 * 168];
    unsigned short Obf[64 * 72];
    float Osum[4][16][64];
    float Mx[8][16];
    float Lx[8][16];
    float biasL[129];
  } p2;
};

#define MLOAD(KS, F0, F1, BB) { \
  _Pragma("unroll") \
  for (int i_ = 0; i_ < 3; ++i_) { \
    const float* a_ = srcA[i_] + (KS) * 64; \
    F0[i_] = *(const float4*)a_; F1[i_] = *(const float4*)(a_ + 4); \
    BB[i_] = *(const uint4*)(srcB[i_] + (KS) * 64); } }

#define MSTORE(BUF, F0, F1, BB) { \
  _Pragma("unroll") \
  for (int i_ = 0; i_ < 3; ++i_) { \
    uint4 p_; \
    p_.x = pk2(F0[i_].x, F0[i_].y); p_.y = pk2(F0[i_].z, F0[i_].w); \
    p_.z = pk2(F1[i_].x, F1[i_].y); p_.w = pk2(F1[i_].z, F1[i_].w); \
    *(uint4*)(sh.p1.A[BUF] + (i_ * 64 + tr) * 72 + cA * 8) = p_; \
    *(uint4*)(sh.p1.B[BUF] + (i_ * 64 + tr) * 72 + cA * 8) = BB[i_]; } }

#define MMMA(BUF) { \
  _Pragma("unroll") \
  for (int kk = 0; kk < 64; kk += 32) { \
    int ko = kk + quad * 8; \
    bf16x8 bfr[3]; \
    _Pragma("unroll") \
    for (int nt = 0; nt < 3; ++nt) \
      bfr[nt] = *(const bf16x8*)(sh.p1.B[BUF] + ((wn * 3 + nt) * 16 + col) * 72 + ko); \
    _Pragma("unroll") \
    for (int mt = 0; mt < 6; ++mt) { \
      bf16x8 afr = *(const bf16x8*)(sh.p1.A[BUF] + ((wm * 6 + mt) * 16 + col) * 72 + ko); \
      _Pragma("unroll") \
      for (int nt = 0; nt < 3; ++nt) \
        acc[mt][nt] = __builtin_amdgcn_mfma_f32_16x16x32_bf16(afr, bfr[nt], acc[mt][nt], 0, 0, 0); \
    } } }

__global__ __launch_bounds__(512, 2) void fused_attn(
    const float* __restrict__ X, const unsigned short* __restrict__ Wt,
    const float* __restrict__ bqkv, const float* __restrict__ bias,
    const unsigned short* __restrict__ Wot, const float* __restrict__ bo,
    float* __restrict__ out)
{
  __shared__ SharedU sh;
  int t = threadIdx.x;
  int lane = t & 63, w = t >> 6;
  int col = lane & 15, quad = lane >> 4, q4 = quad * 4;
  int bidx = blockIdx.x;
  int b = bidx >> 5;                 // batch
  int i0 = (bidx & 31) * 64;         // first q row (batch coords)
  const float* xbase = X + (size_t)(b << 11) * 1024;

  // ---- phase 1: window GEMM ----
  int wm = w >> 2, wn = w & 3;       // wave owns 96 rows x 48 cols
  f32x4 acc[6][3] = {};
  int tr = t >> 3, cA = t & 7;       // 3 tasks/thread: rows tr, tr+64, tr+128
  const float* srcA[3];
  const unsigned short* srcB[3];
  #pragma unroll
  for (int i = 0; i < 3; ++i) {
    int row = i * 64 + tr;           // window row 0..191
    int jb = i0 - 64 + row;
    int jc = jb < 0 ? 0 : (jb > 2047 ? 2047 : jb);
    srcA[i] = xbase + (size_t)jc * 1024 + cA * 8;
    srcB[i] = Wt + (size_t)row * 1024 + cA * 8;
  }
  float bov[3];
  #pragma unroll
  for (int nt = 0; nt < 3; ++nt) bov[nt] = bqkv[wn * 48 + nt * 16 + col];

  float4 eF0[3], eF1[3]; uint4 eB[3];
  float4 oF0[3], oF1[3]; uint4 oB[3];
  MLOAD(0, eF0, eF1, eB);
  MLOAD(1, oF0, oF1, oB);
  for (int ks = 0; ks < 16; ks += 2) {
    MSTORE(0, eF0, eF1, eB);
    if (ks + 2 < 16) MLOAD(ks + 2, eF0, eF1, eB);
    __syncthreads();
    MMMA(0);
    // race-free: prev iter's MMMA(1) is separated from this MSTORE(1)
    // by the barrier above; buffers 0/1 never cross.
    MSTORE(1, oF0, oF1, oB);
    if (ks + 3 < 16) MLOAD(ks + 3, oF0, oF1, oB);
    __syncthreads();
    MMMA(1);
  }
  __syncthreads();   // last MMMA(1) done by all waves before LDS repurpose

  // ---- phase 1b: accumulators (+bias, ->bf16) into phase-2 LDS layouts ----
  if (t < 129) sh.p2.biasL[t] = bias[1984 + t];
  #pragma unroll
  for (int mt = 0; mt < 6; ++mt) {
    #pragma unroll
    for (int nt = 0; nt < 3; ++nt) {
      int n = wn * 48 + nt * 16 + col;
      #pragma unroll
      for (int r = 0; r < 4; ++r) {
        int m = wm * 96 + mt * 16 + q4 + r;      // window row
        unsigned short h = f2bf(acc[mt][nt][r] + bov[nt]);
        if (n < 64) {                            // Q: only middle 64 rows
          bool isq = (wm == 0) ? (mt >= 4) : (mt < 2);
          if (isq) sh.p2.Qs[(m - 64) * 72 + n] = h;
        } else if (n < 128) {
          sh.p2.Kl[m * 72 + (n - 64)] = h;
        } else {
          sh.p2.Vt[(n - 128) * 216 + m] = h;     // transposed
        }
      }
    }
  }
  if (t < 256) { // zero-fill Vt j-cols 192..207 (PV k-chunk overhang)
    int pz = t >> 2, c0 = 192 + (t & 3) * 4;
    *(uint2*)(sh.p2.Vt + pz * 216 + c0) = make_uint2(0u, 0u);
  }
  __syncthreads();

  // ---- phase 2: banded attention (wave-pairs p own 16 q-rows; s splits work) ----
  int p = w >> 1, s = w & 1;
  int iq = i0 + p * 16;                    // pair's first q row (batch coords)
  bf16x8 aq0 = *(const bf16x8*)(sh.p2.Qs + (p * 16 + col) * 72 + quad * 8);
  bf16x8 aq1 = *(const bf16x8*)(sh.p2.Qs + (p * 16 + col) * 72 + 32 + quad * 8);

  // QK^T: wave's j-tile subset (s=0: t9 0..4, s=1: t9 5..8)
  int nt9 = 5 - s, t9b = 5 * s;
  f32x4 sv[5];
  for (int i = 0; i < nt9; ++i) {
    int t9 = t9b + i;
    int krow = ((p + t9) * 16 + col) * 72;
    bf16x8 kb0 = *(const bf16x8*)(sh.p2.Kl + krow + quad * 8);
    bf16x8 kb1 = *(const bf16x8*)(sh.p2.Kl + krow + 32 + quad * 8);
    f32x4 z = {};
    z = __builtin_amdgcn_mfma_f32_16x16x32_bf16(aq0, kb0, z, 0, 0, 0);
    sv[i] = __builtin_amdgcn_mfma_f32_16x16x32_bf16(aq1, kb1, z, 0, 0, 0);
  }
  // mask + bias; partial row max
  float mrow[4] = {-3e38f, -3e38f, -3e38f, -3e38f};
  for (int i = 0; i < nt9; ++i) {
    int t9 = t9b + i;
    int j = iq - 64 + t9 * 16 + col;       // batch coords
    #pragma unroll
    for (int r = 0; r < 4; ++r) {
      int diff = q4 + r + 64 - t9 * 16 - col;   // i - j
      bool valid = (j >= 0) & (j < 2048) & (diff >= -64) & (diff <= 64);
      int bi = 64 - diff; bi = bi < 0 ? 0 : (bi > 128 ? 128 : bi);
      float x = valid ? (sv[i][r] * 0.125f + sh.p2.biasL[bi]) : -3e38f;
      sv[i][r] = x;
      mrow[r] = fmaxf(mrow[r], x);
    }
  }
  #pragma unroll
  for (int r = 0; r < 4; ++r) ROW16_MAX(mrow[r]);
  if (col == 0) {
    #pragma unroll
    for (int r = 0; r < 4; ++r) sh.p2.Mx[w][q4 + r] = mrow[r];
  }
  __syncthreads();
  #pragma unroll
  for (int r = 0; r < 4; ++r) mrow[r] = fmaxf(mrow[r], sh.p2.Mx[w ^ 1][q4 + r]);

  unsigned short* Pw = sh.p2.Ps + p * (16 * 168);
  float lsum[4] = {0.f, 0.f, 0.f, 0.f};
  for (int i = 0; i < nt9; ++i) {
    int t9 = t9b + i;
    #pragma unroll
    for (int r = 0; r < 4; ++r) {
      float pe = __expf(sv[i][r] - mrow[r]);
      lsum[r] += pe;
      Pw[(q4 + r) * 168 + t9 * 16 + col] = f2bf(pe);
    }
  }
  #pragma unroll
  for (int r = 0; r < 4; ++r) ROW16_SUM(lsum[r]);
  if (col == 0) {
    #pragma unroll
    for (int r = 0; r < 4; ++r) sh.p2.Lx[w][q4 + r] = lsum[r];
  }
  if (s == 0) {
    #pragma unroll
    for (int r = 0; r < 4; ++r) Pw[(q4 + r) * 168 + 144 + col] = 0;
  }
  __syncthreads();
  #pragma unroll
  for (int r = 0; r < 4; ++r) lsum[r] += sh.p2.Lx[w ^ 1][q4 + r];

  // PV: wave's k-chunk subset (s=0: kc 0..2, s=1: kc 3..4)
  f32x4 o[4] = {};
  int nkc = 3 - s, kcb = 3 * s;
  for (int i = 0; i < nkc; ++i) {
    int kc = kcb + i;
    bf16x8 pa = *(const bf16x8*)(Pw + col * 168 + kc * 32 + quad * 8);
    #pragma unroll
    for (int nt = 0; nt < 4; ++nt) {
      bf16x8 vb = *(const bf16x8*)(sh.p2.Vt + (nt * 16 + col) * 216 + 16 * p + kc * 32 + quad * 8);
      o[nt] = __builtin_amdgcn_mfma_f32_16x16x32_bf16(pa, vb, o[nt], 0, 0, 0);
    }
  }
  if (s == 1) {
    #pragma unroll
    for (int nt = 0; nt < 4; ++nt)
      #pragma unroll
      for (int r = 0; r < 4; ++r)
        sh.p2.Osum[p][q4 + r][nt * 16 + col] = o[nt][r];
  }
  __syncthreads();
  if (s == 0) { // combine halves, normalize, park O tile in LDS as bf16
    float rl[4];
    #pragma unroll
    for (int r = 0; r < 4; ++r) rl[r] = 1.0f / lsum[r];
    #pragma unroll
    for (int nt = 0; nt < 4; ++nt)
      #pragma unroll
      for (int r = 0; r < 4; ++r)
        sh.p2.Obf[(p * 16 + q4 + r) * 72 + nt * 16 + col] =
            f2bf((o[nt][r] + sh.p2.Osum[p][q4 + r][nt * 16 + col]) * rl[r]);
  }
  __syncthreads();

  // ---- phase 3: output projection  out[64 q][1024 n] = Obf @ Wot + bo ----
  // wave w owns n-cols [w*128, w*128+128); whole Wot slice held in 64 VGPRs.
  const unsigned short* wb_base = Wot + (size_t)(w * 128 + col) * 64 + quad * 8;
  bf16x8 wb[8][2];
  #pragma unroll
  for (int ns = 0; ns < 8; ++ns) {
    wb[ns][0] = *(const bf16x8*)(wb_base + ns * 16 * 64);
    wb[ns][1] = *(const bf16x8*)(wb_base + ns * 16 * 64 + 32);
  }
  float bov8[8];
  #pragma unroll
  for (int ns = 0; ns < 8; ++ns) bov8[ns] = bo[w * 128 + ns * 16 + col];
  float* outbase = out + ((size_t)(b << 11) + i0) * 1024 + w * 128;
  #pragma unroll
  for (int mt = 0; mt < 4; ++mt) {
    bf16x8 a0 = *(const bf16x8*)(sh.p2.Obf + (mt * 16 + col) * 72 + quad * 8);
    bf16x8 a1 = *(const bf16x8*)(sh.p2.Obf + (mt * 16 + col) * 72 + 32 + quad * 8);
    f32x4 acc8[8] = {};
    #pragma unroll
    for (int ns = 0; ns < 8; ++ns) {
      acc8[ns] = __builtin_amdgcn_mfma_f32_16x16x32_bf16(a0, wb[ns][0], acc8[ns], 0, 0, 0);
      acc8[ns] = __builtin_amdgcn_mfma_f32_16x16x32_bf16(a1, wb[ns][1], acc8[ns], 0, 0, 0);
    }
    #pragma unroll
    for (int ns = 0; ns < 8; ++ns)
      #pragma unroll
      for (int r = 0; r < 4; ++r)
        outbase[(size_t)(mt * 16 + q4 + r) * 1024 + ns * 16 + col] = acc8[ns][r] + bov8[ns];
  }
}

// ---------------- launch ----------------
extern "C" void kernel_launch(void* const* d_in, const int* in_sizes, int n_in,
                              void* d_out, int out_size, void* d_ws, size_t ws_size,
                              hipStream_t stream) {
  const float* X    = (const float*)d_in[0];
  // d_in[1] = attention_mask: per-row constant shift -> softmax-invariant, unused
  const float* Wq   = (const float*)d_in[2];
  const float* bq   = (const float*)d_in[3];
  const float* Wk   = (const float*)d_in[4];
  const float* bk   = (const float*)d_in[5];
  const float* Wv   = (const float*)d_in[6];
  const float* bv   = (const float*)d_in[7];
  const float* Wo   = (const float*)d_in[8];
  const float* bo   = (const float*)d_in[9];
  const float* bias = (const float*)d_in[10];
  float* out = (float*)d_out;
  char* ws = (char*)d_ws;
  unsigned short* Wt   = (unsigned short*)(ws);              //   393,216 B
  unsigned short* Wot  = (unsigned short*)(ws + 393216);     //   131,072 B
  float*          bqkv = (float*)(ws + 524288);              //       768 B

  prep_kernel<<<1025, 256, 0, stream>>>(Wq, Wk, Wv, Wo, bq, bk, bv, Wt, Wot, bqkv);
  fused_attn<<<256, 512, 0, stream>>>(X, Wt, bqkv, bias, Wot, bo, out);
}